// Round 16
// baseline (128.466 us; speedup 1.0000x reference)
//
#include <hip/hip_runtime.h>
#include <hip/hip_bf16.h>

#define B_  8
#define T_  2048
#define C_  1024
#define H_  128

using f32x4  = __attribute__((ext_vector_type(4))) float;
using f32x16 = __attribute__((ext_vector_type(16))) float;
using bf16x8 = __attribute__((ext_vector_type(8))) short;

__device__ __forceinline__ unsigned short f2bf(float f) {
    union { float f; unsigned u; } v; v.f = f;
    unsigned r = v.u + 0x7FFFu + ((v.u >> 16) & 1u);   // RNE
    return (unsigned short)(r >> 16);
}
__device__ __forceinline__ float bf2f(unsigned short s) {
    union { unsigned u; float f; } v; v.u = ((unsigned)s) << 16;
    return v.f;
}

// lgkm-only barrier: LDS visibility; register-staged global loads stay in flight
#define BAR() do { asm volatile("s_waitcnt lgkmcnt(0)" ::: "memory"); \
                   __builtin_amdgcn_s_barrier(); } while (0)

// DPP cross-lane reduce within 16-lane rows (VALU-speed)
template<int C>
__device__ __forceinline__ float dppf(float v) {
    return __int_as_float(__builtin_amdgcn_update_dpp(0, __float_as_int(v), C, 0xF, 0xF, true));
}
#define DPPRED_MAX(v) { v = fmaxf(v, dppf<0xB1>(v)); v = fmaxf(v, dppf<0x4E>(v)); \
                        v = fmaxf(v, dppf<0x141>(v)); v = fmaxf(v, dppf<0x140>(v)); }
#define DPPRED_SUM(v) { v = v + dppf<0xB1>(v); v = v + dppf<0x4E>(v); \
                        v = v + dppf<0x141>(v); v = v + dppf<0x140>(v); }

// ---------------------------------------------------------------------------
// W{q,k,v} fp32 [1024][128] -> Wt K-TILED bf16: Wt[k>>5][col][k&31]
// (each 384x32 B-tile = contiguous 24 KB stream). Wq pre-scaled 1/32.
// ---------------------------------------------------------------------------
__global__ void wconv_kernel(const float* __restrict__ Wq,
                             const float* __restrict__ Wk,
                             const float* __restrict__ Wv,
                             unsigned short* __restrict__ Wt) {
    int id  = blockIdx.x * 256 + threadIdx.x;
    int col = id % 384;
    int k   = id / 384;
    const float* W = (col < 128) ? Wq : ((col < 256) ? Wk : Wv);
    float v = W[k * H_ + (col & 127)];
    if (col < 128) v *= 0.03125f;   // fold C^-0.5 into Wq (exact pow2)
    Wt[(size_t)(k >> 5) * 12288 + col * 32 + (k & 31)] = f2bf(v);
}

// ---------------------------------------------------------------------------
// Fused projection GEMM — 32x32x16 MFMA, BM=64 (R15 skeleton) with fixed
// prefetch pipeline: B regs loaded 1 full step before their LDS write
// (brA = write now, brN = load now); x 3-deep. #pragma unroll 2 makes all
// rotations static renames — no same-step VMEM register waits remain.
// ---------------------------------------------------------------------------
__launch_bounds__(512, 2)
__global__ void gemm_kernel(const float* __restrict__ x,
                            const unsigned short* __restrict__ Wt,
                            unsigned short* __restrict__ qb,
                            unsigned short* __restrict__ kb,
                            unsigned short* __restrict__ vT) {
    __shared__ unsigned short Bs[2][13824];   // [384 col][36], pad 32->36
    __shared__ unsigned short As[2][2304];    // [64 row][36]

    const int tid  = threadIdx.x;
    const int wave = tid >> 6;
    const int lane = tid & 63;
    const int r32 = lane & 31, hi32 = lane >> 5;
    const int row0 = blockIdx.x * 64;
    const int wrow  = (wave >> 2) * 32;
    const int wcol0 = (wave & 3) * 96;

    const int arow = tid >> 3;
    const int ak4  = (tid & 7) * 4;
    const float* xsrc = x + (size_t)(row0 + arow) * C_ + ak4;
    const unsigned short* bsrc = Wt + (size_t)tid * 8;

    f32x16 acc[3];
    #pragma unroll
    for (int ct = 0; ct < 3; ++ct)
        #pragma unroll
        for (int e = 0; e < 16; ++e) acc[ct][e] = 0.f;

    // prologue: stage step 0 directly; brA = B(1); x(1), x(2) into regs
    {
        #pragma unroll
        for (int j = 0; j < 3; ++j) {
            const int chunk = tid + j * 512;
            *(uint4*)&Bs[0][(chunk >> 2) * 36 + (chunk & 3) * 8] =
                *(const uint4*)(bsrc + j * 4096);
        }
        float4 f = *(const float4*)(xsrc);
        unsigned a0 = f2bf(f.x) | ((unsigned)f2bf(f.y) << 16);
        unsigned a1 = f2bf(f.z) | ((unsigned)f2bf(f.w) << 16);
        *(uint2*)&As[0][arow * 36 + ak4] = uint2{a0, a1};
    }
    uint4 brA[3];
    #pragma unroll
    for (int j = 0; j < 3; ++j)
        brA[j] = *(const uint4*)(bsrc + 12288 + j * 4096);
    float4 hA = *(const float4*)(xsrc + 32);
    float4 hB = *(const float4*)(xsrc + 64);
    BAR();

    #pragma unroll 2
    for (int k = 0; k < 32; ++k) {
        const int cur = k & 1, nxt = cur ^ 1;

        // loads: B(k+2) [clamped] and x(k+3) [clamped] — consumed NEXT step
        uint4 brN[3];
        {
            const int kb2 = (k + 2 < 31) ? k + 2 : 31;
            const unsigned short* g = bsrc + (size_t)kb2 * 12288;
            #pragma unroll
            for (int j = 0; j < 3; ++j) brN[j] = *(const uint4*)(g + j * 4096);
        }
        const int kn = (k + 3 < 31) ? k + 3 : 31;
        float4 xf = *(const float4*)(xsrc + kn * 32);

        // MFMA: 2 k-halves x 3 col-tiles of 32
        #pragma unroll
        for (int kh = 0; kh < 2; ++kh) {
            const int kofs = kh * 16 + 8 * hi32;
            bf16x8 af = *(const bf16x8*)&As[cur][(wrow + r32) * 36 + kofs];
            #pragma unroll
            for (int ct = 0; ct < 3; ++ct) {
                bf16x8 bf = *(const bf16x8*)&Bs[cur][(wcol0 + ct * 32 + r32) * 36 + kofs];
                acc[ct] = __builtin_amdgcn_mfma_f32_32x32x16_bf16(af, bf, acc[ct], 0, 0, 0);
            }
        }

        // write step k+1 buffers from regs loaded >=1 full step ago
        if (k < 31) {
            #pragma unroll
            for (int j = 0; j < 3; ++j) {
                const int chunk = tid + j * 512;
                *(uint4*)&Bs[nxt][(chunk >> 2) * 36 + (chunk & 3) * 8] = brA[j];
            }
            unsigned a0 = f2bf(hA.x) | ((unsigned)f2bf(hA.y) << 16);
            unsigned a1 = f2bf(hA.z) | ((unsigned)f2bf(hA.w) << 16);
            *(uint2*)&As[nxt][arow * 36 + ak4] = uint2{a0, a1};
        }
        BAR();
        // static renames under unroll 2
        brA[0] = brN[0]; brA[1] = brN[1]; brA[2] = brN[2];
        hA = hB; hB = xf;
    }

    // epilogue: C/D col = lane&31, row = (reg&3) + 8*(reg>>2) + 4*(lane>>5)
    #pragma unroll
    for (int ct = 0; ct < 3; ++ct) {
        int col = wcol0 + ct * 32 + r32;
        int head = col >> 7;
        int h = col & 127;
        #pragma unroll
        for (int reg = 0; reg < 16; ++reg) {
            int rg = row0 + wrow + (reg & 3) + 8 * (reg >> 2) + 4 * hi32;
            unsigned short val = f2bf(acc[ct][reg]);
            if (head == 0)      qb[(size_t)rg * H_ + h] = val;
            else if (head == 1) kb[(size_t)rg * H_ + h] = val;
            else {
                int b = rg >> 11, t = rg & (T_ - 1);
                vT[((size_t)b * H_ + h) * T_ + t] = val;
            }
        }
    }
}

// ---------------------------------------------------------------------------
// Flash pass 1 (R15 form; Opart now bf16). Block = 8 waves; QBLK=256;
// chunk = 256 kv = 4 x KV64 tiles. Grid 512, empties exit.
// ---------------------------------------------------------------------------
__launch_bounds__(512, 2)
__global__ void attn1_kernel(const unsigned short* __restrict__ qb,
                             const unsigned short* __restrict__ kb,
                             const unsigned short* __restrict__ vT,
                             unsigned short* __restrict__ Opart,
                             float* __restrict__ MLpart) {
    __shared__ unsigned short Ks[64 * 128];   // [kv][k], 16B chunks XOR-swizzled
    __shared__ unsigned short Vs[128 * 64];   // [h][kv], swizzled
    __shared__ unsigned short Ps[8][16][72];  // per-wave P transpose (2-pass)

    const int tid  = threadIdx.x;
    const int wave = tid >> 6;
    const int lane = tid & 63;
    const int lo = lane & 15, hi = lane >> 4;

    const int bid   = blockIdx.x;
    const int b     = bid & 7;
    const int chunk = (bid >> 3) & 7;
    const int qt    = 7 - (bid >> 6);
    if (chunk > qt) return;

    const int kv_begin = chunk << 8;
    const size_t bT = (size_t)b * T_;
    const int qrow0 = (qt << 8) + wave * 32;

    const int krow = tid >> 3, kcol = (tid & 7) * 2;
    const int vrow = tid >> 2, vcol = (tid & 3) * 2;
    const unsigned short* kgsrc = kb + (bT + krow) * H_ + kcol * 8;
    const unsigned short* vgsrc = vT + ((size_t)b * H_ + vrow) * T_ + vcol * 8;
    unsigned short* kdst0 = &Ks[krow * 128 + ((kcol ^ (krow & 7)) * 8)];
    unsigned short* kdst1 = &Ks[krow * 128 + (((kcol + 1) ^ (krow & 7)) * 8)];
    unsigned short* vdst0 = &Vs[vrow * 64 + ((vcol ^ (vrow & 7)) * 8)];
    unsigned short* vdst1 = &Vs[vrow * 64 + (((vcol + 1) ^ (vrow & 7)) * 8)];

    bf16x8 qf[2][4];
    #pragma unroll
    for (int q2 = 0; q2 < 2; ++q2)
        #pragma unroll
        for (int kc = 0; kc < 4; ++kc)
            qf[q2][kc] = *(const bf16x8*)(qb + (bT + qrow0 + 16 * q2 + lo) * H_ + kc * 32 + 8 * hi);

    float m[2][4], l[2][4];
    f32x4 o[2][8];
    #pragma unroll
    for (int q2 = 0; q2 < 2; ++q2)
        #pragma unroll
        for (int r = 0; r < 4; ++r) { m[q2][r] = -1e30f; l[q2][r] = 0.f; }
    #pragma unroll
    for (int q2 = 0; q2 < 2; ++q2)
        #pragma unroll
        for (int ct = 0; ct < 8; ++ct) o[q2][ct] = f32x4{0.f, 0.f, 0.f, 0.f};

    uint4 kr0 = *(const uint4*)(kgsrc + (size_t)kv_begin * H_);
    uint4 kr1 = *(const uint4*)(kgsrc + (size_t)kv_begin * H_ + 8);
    uint4 vr0 = *(const uint4*)(vgsrc + kv_begin);
    uint4 vr1 = *(const uint4*)(vgsrc + kv_begin + 8);

    for (int t = 0; t < 4; ++t) {
        const int kv0 = kv_begin + t * 64;
        BAR();
        *(uint4*)kdst0 = kr0;
        *(uint4*)kdst1 = kr1;
        *(uint4*)vdst0 = vr0;
        *(uint4*)vdst1 = vr1;
        BAR();
        if (t < 3) {
            const int kvn = kv0 + 64;
            kr0 = *(const uint4*)(kgsrc + (size_t)kvn * H_);
            kr1 = *(const uint4*)(kgsrc + (size_t)kvn * H_ + 8);
            vr0 = *(const uint4*)(vgsrc + kvn);
            vr1 = *(const uint4*)(vgsrc + kvn + 8);
        }
        if (kv0 > qrow0 + 31) continue;

        f32x4 s[2][4];
        #pragma unroll
        for (int q2 = 0; q2 < 2; ++q2)
            #pragma unroll
            for (int ct4 = 0; ct4 < 4; ++ct4) s[q2][ct4] = f32x4{0.f, 0.f, 0.f, 0.f};
        __builtin_amdgcn_s_setprio(1);
        #pragma unroll
        for (int ct4 = 0; ct4 < 4; ++ct4) {
            const int row = ct4 * 16 + lo;
            #pragma unroll
            for (int kc = 0; kc < 4; ++kc) {
                bf16x8 kf = *(const bf16x8*)&Ks[row * 128 + (((kc * 4 + hi) ^ (row & 7)) * 8)];
                s[0][ct4] = __builtin_amdgcn_mfma_f32_16x16x32_bf16(qf[0][kc], kf, s[0][ct4], 0, 0, 0);
                s[1][ct4] = __builtin_amdgcn_mfma_f32_16x16x32_bf16(qf[1][kc], kf, s[1][ct4], 0, 0, 0);
            }
        }
        __builtin_amdgcn_s_setprio(0);

        if (kv0 + 63 >= qrow0) {
            #pragma unroll
            for (int q2 = 0; q2 < 2; ++q2)
                #pragma unroll
                for (int ct4 = 0; ct4 < 4; ++ct4)
                    #pragma unroll
                    for (int r = 0; r < 4; ++r)
                        if (kv0 + ct4 * 16 + lo > qrow0 + 16 * q2 + 4 * hi + r)
                            s[q2][ct4][r] = -1e30f;
        }

        float alpha[2][4];
        #pragma unroll
        for (int q2 = 0; q2 < 2; ++q2) {
            #pragma unroll
            for (int r = 0; r < 4; ++r) {
                float pm = fmaxf(fmaxf(s[q2][0][r], s[q2][1][r]), fmaxf(s[q2][2][r], s[q2][3][r]));
                DPPRED_MAX(pm);
                float mn = fmaxf(m[q2][r], pm);
                alpha[q2][r] = __expf(m[q2][r] - mn);
                m[q2][r] = mn;
                #pragma unroll
                for (int ct4 = 0; ct4 < 4; ++ct4) s[q2][ct4][r] = __expf(s[q2][ct4][r] - mn);
                float rs = (s[q2][0][r] + s[q2][1][r]) + (s[q2][2][r] + s[q2][3][r]);
                DPPRED_SUM(rs);
                l[q2][r] = l[q2][r] * alpha[q2][r] + rs;
            }
        }
        #pragma unroll
        for (int q2 = 0; q2 < 2; ++q2)
            #pragma unroll
            for (int ct = 0; ct < 8; ++ct)
                #pragma unroll
                for (int r = 0; r < 4; ++r) o[q2][ct][r] *= alpha[q2][r];

        bf16x8 pa[2][2];
        #pragma unroll
        for (int q2 = 0; q2 < 2; ++q2) {
            #pragma unroll
            for (int ct4 = 0; ct4 < 4; ++ct4)
                #pragma unroll
                for (int r = 0; r < 4; ++r)
                    Ps[wave][4 * hi + r][ct4 * 16 + lo] = f2bf(s[q2][ct4][r]);
            pa[q2][0] = *(const bf16x8*)&Ps[wave][lo][8 * hi];
            pa[q2][1] = *(const bf16x8*)&Ps[wave][lo][32 + 8 * hi];
        }

        __builtin_amdgcn_s_setprio(1);
        #pragma unroll
        for (int ct = 0; ct < 8; ++ct) {
            const int row = ct * 16 + lo;
            #pragma unroll
            for (int half = 0; half < 2; ++half) {
                bf16x8 vf = *(const bf16x8*)&Vs[row * 64 + (((half * 4 + hi) ^ (row & 7)) * 8)];
                o[0][ct] = __builtin_amdgcn_mfma_f32_16x16x32_bf16(pa[0][half], vf, o[0][ct], 0, 0, 0);
                o[1][ct] = __builtin_amdgcn_mfma_f32_16x16x32_bf16(pa[1][half], vf, o[1][ct], 0, 0, 0);
            }
        }
        __builtin_amdgcn_s_setprio(0);
    }

    // write partial state (Opart bf16: values bounded, |err/L| ~ 2^-9 * |v|)
    const int slot = b * 36 + ((qt * (qt + 1)) >> 1) + chunk;
    unsigned short* op = Opart + (size_t)slot * 32768 + (size_t)(wave * 32) * 128;
    #pragma unroll
    for (int q2 = 0; q2 < 2; ++q2)
        #pragma unroll
        for (int ct = 0; ct < 8; ++ct)
            #pragma unroll
            for (int r = 0; r < 4; ++r)
                op[(16 * q2 + 4 * hi + r) * 128 + ct * 16 + lo] = f2bf(o[q2][ct][r]);
    if (lo == 0) {
        #pragma unroll
        for (int q2 = 0; q2 < 2; ++q2)
            #pragma unroll
            for (int r = 0; r < 4; ++r) {
                int base = slot * 512 + (wave * 32 + 16 * q2 + 4 * hi + r) * 2;
                MLpart[base]     = m[q2][r];
                MLpart[base + 1] = l[q2][r];
            }
    }
}

// ---------------------------------------------------------------------------
// Flash pass 2: merge <= 8 bf16 chunk partials. 512 blocks x 128 thr.
// ---------------------------------------------------------------------------
__launch_bounds__(128)
__global__ void attn2_kernel(const unsigned short* __restrict__ Opart,
                             const float* __restrict__ MLpart,
                             float* __restrict__ out) {
    const int bid = blockIdx.x;
    const int b   = bid & 7;
    const int qt  = (bid >> 3) & 7;
    const int sub = bid >> 6;              // 0..7
    const int nch = qt + 1;
    const int slot0 = b * 36 + ((qt * (qt + 1)) >> 1);

    const int tid  = threadIdx.x;
    const int row  = tid >> 2;             // 0..31
    const int h0   = (tid & 3) * 32;
    const int srow = sub * 32 + row;       // row within slot

    float M = -1e30f;
    for (int c = 0; c < nch; ++c)
        M = fmaxf(M, MLpart[(slot0 + c) * 512 + srow * 2]);
    float L = 0.f;
    for (int c = 0; c < nch; ++c) {
        float mc = MLpart[(slot0 + c) * 512 + srow * 2];
        float lc = MLpart[(slot0 + c) * 512 + srow * 2 + 1];
        L += lc * __expf(mc - M);
    }

    float accv[32];
    #pragma unroll
    for (int j = 0; j < 32; ++j) accv[j] = 0.f;
    for (int c = 0; c < nch; ++c) {
        float wc = __expf(MLpart[(slot0 + c) * 512 + srow * 2] - M);
        const unsigned short* src = Opart + (size_t)(slot0 + c) * 32768 + (size_t)srow * 128 + h0;
        #pragma unroll
        for (int j = 0; j < 4; ++j) {
            bf16x8 v = *(const bf16x8*)(src + j * 8);
            #pragma unroll
            for (int e = 0; e < 8; ++e)
                accv[j * 8 + e] += wc * bf2f((unsigned short)v[e]);
        }
    }
    float inv = 1.f / L;
    float4* dst = (float4*)(out + ((size_t)b * T_ + qt * 256 + srow) * H_ + h0);
    #pragma unroll
    for (int j = 0; j < 8; ++j)
        dst[j] = float4{accv[4 * j] * inv, accv[4 * j + 1] * inv,
                        accv[4 * j + 2] * inv, accv[4 * j + 3] * inv};
}

extern "C" void kernel_launch(void* const* d_in, const int* in_sizes, int n_in,
                              void* d_out, int out_size, void* d_ws, size_t ws_size,
                              hipStream_t stream) {
    const float* x  = (const float*)d_in[0];
    const float* Wq = (const float*)d_in[1];
    const float* Wk = (const float*)d_in[2];
    const float* Wv = (const float*)d_in[3];
    float* out = (float*)d_out;

    char* ws = (char*)d_ws;
    unsigned short* Wt  = (unsigned short*)ws;                          // 0.75 MB
    unsigned short* qbf = (unsigned short*)(ws + (size_t)384 * 1024 * 2);
    unsigned short* kbf = qbf + (size_t)B_ * T_ * H_;
    unsigned short* vTf = kbf + (size_t)B_ * T_ * H_;
    unsigned short* Opart = vTf + (size_t)B_ * T_ * H_;                 // 18 MB bf16
    float* MLpart = (float*)((char*)Opart + (size_t)288 * 32768 * 2);   // 0.56 MB

    wconv_kernel<<<(384 * 1024) / 256, 256, 0, stream>>>(Wq, Wk, Wv, Wt);
    gemm_kernel<<<B_ * T_ / 64, 512, 0, stream>>>(x, Wt, qbf, kbf, vTf);
    attn1_kernel<<<512, 512, 0, stream>>>(qbf, kbf, vTf, Opart, MLpart);
    attn2_kernel<<<512, 128, 0, stream>>>(Opart, MLpart, out);
}

// Round 17
// 93.125 us; speedup vs baseline: 1.3795x; 1.3795x over previous
//
#include <hip/hip_runtime.h>
#include <hip/hip_bf16.h>

#define B_  8
#define T_  2048
#define C_  1024
#define H_  128

using f32x4  = __attribute__((ext_vector_type(4))) float;
using f32x16 = __attribute__((ext_vector_type(16))) float;
using bf16x8 = __attribute__((ext_vector_type(8))) short;

__device__ __forceinline__ unsigned short f2bf(float f) {
    union { float f; unsigned u; } v; v.f = f;
    unsigned r = v.u + 0x7FFFu + ((v.u >> 16) & 1u);   // RNE
    return (unsigned short)(r >> 16);
}
__device__ __forceinline__ float bf2f(unsigned short s) {
    union { unsigned u; float f; } v; v.u = ((unsigned)s) << 16;
    return v.f;
}

// lgkm-only barrier: LDS visibility; register-staged global loads stay in flight
#define BAR() do { asm volatile("s_waitcnt lgkmcnt(0)" ::: "memory"); \
                   __builtin_amdgcn_s_barrier(); } while (0)

// DPP cross-lane reduce within 16-lane rows (VALU-speed)
template<int C>
__device__ __forceinline__ float dppf(float v) {
    return __int_as_float(__builtin_amdgcn_update_dpp(0, __float_as_int(v), C, 0xF, 0xF, true));
}
#define DPPRED_MAX(v) { v = fmaxf(v, dppf<0xB1>(v)); v = fmaxf(v, dppf<0x4E>(v)); \
                        v = fmaxf(v, dppf<0x141>(v)); v = fmaxf(v, dppf<0x140>(v)); }
#define DPPRED_SUM(v) { v = v + dppf<0xB1>(v); v = v + dppf<0x4E>(v); \
                        v = v + dppf<0x141>(v); v = v + dppf<0x140>(v); }

// ---------------------------------------------------------------------------
// W{q,k,v} fp32 [1024][128] -> Wt K-TILED bf16: Wt[k>>5][col][k&31]
// (each 384x32 B-tile = contiguous 24 KB stream). Wq pre-scaled 1/32.
// ---------------------------------------------------------------------------
__global__ void wconv_kernel(const float* __restrict__ Wq,
                             const float* __restrict__ Wk,
                             const float* __restrict__ Wv,
                             unsigned short* __restrict__ Wt) {
    int id  = blockIdx.x * 256 + threadIdx.x;
    int col = id % 384;
    int k   = id / 384;
    const float* W = (col < 128) ? Wq : ((col < 256) ? Wk : Wv);
    float v = W[k * H_ + (col & 127)];
    if (col < 128) v *= 0.03125f;   // fold C^-0.5 into Wq (exact pow2)
    Wt[(size_t)(k >> 5) * 12288 + col * 32 + (k & 31)] = f2bf(v);
}

// ---------------------------------------------------------------------------
// Fused projection GEMM — R15-exact (proven 44.8 us). 32x32x16 MFMA, BM=64.
// Grid 256 x 512 thr (8 waves: 2 row-groups x 4 col-panels; wave = 32r x 96c,
// acc = 3 x f32x16). BK=32, 32 steps, dbuf, 1 lgkm-barrier/step.
// ---------------------------------------------------------------------------
__launch_bounds__(512, 2)
__global__ void gemm_kernel(const float* __restrict__ x,
                            const unsigned short* __restrict__ Wt,
                            unsigned short* __restrict__ qb,
                            unsigned short* __restrict__ kb,
                            unsigned short* __restrict__ vT) {
    __shared__ unsigned short Bs[2][13824];   // [384 col][36], pad 32->36
    __shared__ unsigned short As[2][2304];    // [64 row][36]

    const int tid  = threadIdx.x;
    const int wave = tid >> 6;
    const int lane = tid & 63;
    const int r32 = lane & 31, hi32 = lane >> 5;
    const int row0 = blockIdx.x * 64;
    const int wrow  = (wave >> 2) * 32;
    const int wcol0 = (wave & 3) * 96;

    const int arow = tid >> 3;
    const int ak4  = (tid & 7) * 4;
    const float* xsrc = x + (size_t)(row0 + arow) * C_ + ak4;
    const unsigned short* bsrc = Wt + (size_t)tid * 8;

    f32x16 acc[3];
    #pragma unroll
    for (int ct = 0; ct < 3; ++ct)
        #pragma unroll
        for (int e = 0; e < 16; ++e) acc[ct][e] = 0.f;

    {
        #pragma unroll
        for (int j = 0; j < 3; ++j) {
            const int chunk = tid + j * 512;
            *(uint4*)&Bs[0][(chunk >> 2) * 36 + (chunk & 3) * 8] =
                *(const uint4*)(bsrc + j * 4096);
        }
        float4 f = *(const float4*)(xsrc);
        unsigned a0 = f2bf(f.x) | ((unsigned)f2bf(f.y) << 16);
        unsigned a1 = f2bf(f.z) | ((unsigned)f2bf(f.w) << 16);
        *(uint2*)&As[0][arow * 36 + ak4] = uint2{a0, a1};
    }
    float4 hA = *(const float4*)(xsrc + 32);
    float4 hB = *(const float4*)(xsrc + 64);
    BAR();

    for (int k = 0; k < 32; ++k) {
        const int cur = k & 1, nxt = cur ^ 1;

        uint4 br[3];
        float4 xf;
        if (k < 31) {
            const unsigned short* g = bsrc + (size_t)(k + 1) * 12288;
            #pragma unroll
            for (int j = 0; j < 3; ++j) br[j] = *(const uint4*)(g + j * 4096);
        }
        {
            const int kn = (k + 3 < 31) ? k + 3 : 31;
            xf = *(const float4*)(xsrc + kn * 32);
        }

        #pragma unroll
        for (int kh = 0; kh < 2; ++kh) {
            const int kofs = kh * 16 + 8 * hi32;
            bf16x8 af = *(const bf16x8*)&As[cur][(wrow + r32) * 36 + kofs];
            #pragma unroll
            for (int ct = 0; ct < 3; ++ct) {
                bf16x8 bf = *(const bf16x8*)&Bs[cur][(wcol0 + ct * 32 + r32) * 36 + kofs];
                acc[ct] = __builtin_amdgcn_mfma_f32_32x32x16_bf16(af, bf, acc[ct], 0, 0, 0);
            }
        }

        if (k < 31) {
            #pragma unroll
            for (int j = 0; j < 3; ++j) {
                const int chunk = tid + j * 512;
                *(uint4*)&Bs[nxt][(chunk >> 2) * 36 + (chunk & 3) * 8] = br[j];
            }
            unsigned a0 = f2bf(hA.x) | ((unsigned)f2bf(hA.y) << 16);
            unsigned a1 = f2bf(hA.z) | ((unsigned)f2bf(hA.w) << 16);
            *(uint2*)&As[nxt][arow * 36 + ak4] = uint2{a0, a1};
        }
        BAR();
        hA = hB; hB = xf;
    }

    #pragma unroll
    for (int ct = 0; ct < 3; ++ct) {
        int col = wcol0 + ct * 32 + r32;
        int head = col >> 7;
        int h = col & 127;
        #pragma unroll
        for (int reg = 0; reg < 16; ++reg) {
            int rg = row0 + wrow + (reg & 3) + 8 * (reg >> 2) + 4 * hi32;
            unsigned short val = f2bf(acc[ct][reg]);
            if (head == 0)      qb[(size_t)rg * H_ + h] = val;
            else if (head == 1) kb[(size_t)rg * H_ + h] = val;
            else {
                int b = rg >> 11, t = rg & (T_ - 1);
                vT[((size_t)b * H_ + h) * T_ + t] = val;
            }
        }
    }
}

// ---------------------------------------------------------------------------
// Flash pass 1 — chunk = 128 kv (2 x KV64 tiles). Grid 1024 (heavy qt first):
// 576 real blocks (~2.25/CU) vs 288 before — latency-bound kernel gets 2x TLP.
// Block = 8 waves; QBLK=256 (32 q-rows/wave). Partials (m,l,O) bf16 O.
// ---------------------------------------------------------------------------
__launch_bounds__(512, 2)
__global__ void attn1_kernel(const unsigned short* __restrict__ qb,
                             const unsigned short* __restrict__ kb,
                             const unsigned short* __restrict__ vT,
                             unsigned short* __restrict__ Opart,
                             float* __restrict__ MLpart) {
    __shared__ unsigned short Ks[64 * 128];   // [kv][k], 16B chunks XOR-swizzled
    __shared__ unsigned short Vs[128 * 64];   // [h][kv], swizzled
    __shared__ unsigned short Ps[8][16][72];  // per-wave P transpose (2-pass)

    const int tid  = threadIdx.x;
    const int wave = tid >> 6;
    const int lane = tid & 63;
    const int lo = lane & 15, hi = lane >> 4;

    const int bid   = blockIdx.x;
    const int b     = bid & 7;
    const int chunk = (bid >> 3) & 15;
    const int qt    = 7 - (bid >> 7);
    const int nch   = 2 * (qt + 1);
    if (chunk >= nch) return;

    const int kv_begin = chunk << 7;          // 128-kv chunk
    const size_t bT = (size_t)b * T_;
    const int qrow0 = (qt << 8) + wave * 32;

    const int krow = tid >> 3, kcol = (tid & 7) * 2;
    const int vrow = tid >> 2, vcol = (tid & 3) * 2;
    const unsigned short* kgsrc = kb + (bT + krow) * H_ + kcol * 8;
    const unsigned short* vgsrc = vT + ((size_t)b * H_ + vrow) * T_ + vcol * 8;
    unsigned short* kdst0 = &Ks[krow * 128 + ((kcol ^ (krow & 7)) * 8)];
    unsigned short* kdst1 = &Ks[krow * 128 + (((kcol + 1) ^ (krow & 7)) * 8)];
    unsigned short* vdst0 = &Vs[vrow * 64 + ((vcol ^ (vrow & 7)) * 8)];
    unsigned short* vdst1 = &Vs[vrow * 64 + (((vcol + 1) ^ (vrow & 7)) * 8)];

    bf16x8 qf[2][4];
    #pragma unroll
    for (int q2 = 0; q2 < 2; ++q2)
        #pragma unroll
        for (int kc = 0; kc < 4; ++kc)
            qf[q2][kc] = *(const bf16x8*)(qb + (bT + qrow0 + 16 * q2 + lo) * H_ + kc * 32 + 8 * hi);

    float m[2][4], l[2][4];
    f32x4 o[2][8];
    #pragma unroll
    for (int q2 = 0; q2 < 2; ++q2)
        #pragma unroll
        for (int r = 0; r < 4; ++r) { m[q2][r] = -1e30f; l[q2][r] = 0.f; }
    #pragma unroll
    for (int q2 = 0; q2 < 2; ++q2)
        #pragma unroll
        for (int ct = 0; ct < 8; ++ct) o[q2][ct] = f32x4{0.f, 0.f, 0.f, 0.f};

    uint4 kr0 = *(const uint4*)(kgsrc + (size_t)kv_begin * H_);
    uint4 kr1 = *(const uint4*)(kgsrc + (size_t)kv_begin * H_ + 8);
    uint4 vr0 = *(const uint4*)(vgsrc + kv_begin);
    uint4 vr1 = *(const uint4*)(vgsrc + kv_begin + 8);

    for (int t = 0; t < 2; ++t) {
        const int kv0 = kv_begin + t * 64;
        BAR();
        *(uint4*)kdst0 = kr0;
        *(uint4*)kdst1 = kr1;
        *(uint4*)vdst0 = vr0;
        *(uint4*)vdst1 = vr1;
        BAR();
        if (t < 1) {
            const int kvn = kv0 + 64;
            kr0 = *(const uint4*)(kgsrc + (size_t)kvn * H_);
            kr1 = *(const uint4*)(kgsrc + (size_t)kvn * H_ + 8);
            vr0 = *(const uint4*)(vgsrc + kvn);
            vr1 = *(const uint4*)(vgsrc + kvn + 8);
        }
        if (kv0 > qrow0 + 31) continue;

        f32x4 s[2][4];
        #pragma unroll
        for (int q2 = 0; q2 < 2; ++q2)
            #pragma unroll
            for (int ct4 = 0; ct4 < 4; ++ct4) s[q2][ct4] = f32x4{0.f, 0.f, 0.f, 0.f};
        __builtin_amdgcn_s_setprio(1);
        #pragma unroll
        for (int ct4 = 0; ct4 < 4; ++ct4) {
            const int row = ct4 * 16 + lo;
            #pragma unroll
            for (int kc = 0; kc < 4; ++kc) {
                bf16x8 kf = *(const bf16x8*)&Ks[row * 128 + (((kc * 4 + hi) ^ (row & 7)) * 8)];
                s[0][ct4] = __builtin_amdgcn_mfma_f32_16x16x32_bf16(qf[0][kc], kf, s[0][ct4], 0, 0, 0);
                s[1][ct4] = __builtin_amdgcn_mfma_f32_16x16x32_bf16(qf[1][kc], kf, s[1][ct4], 0, 0, 0);
            }
        }
        __builtin_amdgcn_s_setprio(0);

        if (kv0 + 63 >= qrow0) {
            #pragma unroll
            for (int q2 = 0; q2 < 2; ++q2)
                #pragma unroll
                for (int ct4 = 0; ct4 < 4; ++ct4)
                    #pragma unroll
                    for (int r = 0; r < 4; ++r)
                        if (kv0 + ct4 * 16 + lo > qrow0 + 16 * q2 + 4 * hi + r)
                            s[q2][ct4][r] = -1e30f;
        }

        float alpha[2][4];
        #pragma unroll
        for (int q2 = 0; q2 < 2; ++q2) {
            #pragma unroll
            for (int r = 0; r < 4; ++r) {
                float pm = fmaxf(fmaxf(s[q2][0][r], s[q2][1][r]), fmaxf(s[q2][2][r], s[q2][3][r]));
                DPPRED_MAX(pm);
                float mn = fmaxf(m[q2][r], pm);
                alpha[q2][r] = __expf(m[q2][r] - mn);
                m[q2][r] = mn;
                #pragma unroll
                for (int ct4 = 0; ct4 < 4; ++ct4) s[q2][ct4][r] = __expf(s[q2][ct4][r] - mn);
                float rs = (s[q2][0][r] + s[q2][1][r]) + (s[q2][2][r] + s[q2][3][r]);
                DPPRED_SUM(rs);
                l[q2][r] = l[q2][r] * alpha[q2][r] + rs;
            }
        }
        #pragma unroll
        for (int q2 = 0; q2 < 2; ++q2)
            #pragma unroll
            for (int ct = 0; ct < 8; ++ct)
                #pragma unroll
                for (int r = 0; r < 4; ++r) o[q2][ct][r] *= alpha[q2][r];

        bf16x8 pa[2][2];
        #pragma unroll
        for (int q2 = 0; q2 < 2; ++q2) {
            #pragma unroll
            for (int ct4 = 0; ct4 < 4; ++ct4)
                #pragma unroll
                for (int r = 0; r < 4; ++r)
                    Ps[wave][4 * hi + r][ct4 * 16 + lo] = f2bf(s[q2][ct4][r]);
            pa[q2][0] = *(const bf16x8*)&Ps[wave][lo][8 * hi];
            pa[q2][1] = *(const bf16x8*)&Ps[wave][lo][32 + 8 * hi];
        }

        __builtin_amdgcn_s_setprio(1);
        #pragma unroll
        for (int ct = 0; ct < 8; ++ct) {
            const int row = ct * 16 + lo;
            #pragma unroll
            for (int half = 0; half < 2; ++half) {
                bf16x8 vf = *(const bf16x8*)&Vs[row * 64 + (((half * 4 + hi) ^ (row & 7)) * 8)];
                o[0][ct] = __builtin_amdgcn_mfma_f32_16x16x32_bf16(pa[0][half], vf, o[0][ct], 0, 0, 0);
                o[1][ct] = __builtin_amdgcn_mfma_f32_16x16x32_bf16(pa[1][half], vf, o[1][ct], 0, 0, 0);
            }
        }
        __builtin_amdgcn_s_setprio(0);
    }

    // partial state: slot = b*72 + qt(qt+1) + chunk  (nch(qt) = 2(qt+1))
    const int slot = b * 72 + qt * (qt + 1) + chunk;
    unsigned short* op = Opart + (size_t)slot * 32768 + (size_t)(wave * 32) * 128;
    #pragma unroll
    for (int q2 = 0; q2 < 2; ++q2)
        #pragma unroll
        for (int ct = 0; ct < 8; ++ct)
            #pragma unroll
            for (int r = 0; r < 4; ++r)
                op[(16 * q2 + 4 * hi + r) * 128 + ct * 16 + lo] = f2bf(o[q2][ct][r]);
    if (lo == 0) {
        #pragma unroll
        for (int q2 = 0; q2 < 2; ++q2)
            #pragma unroll
            for (int r = 0; r < 4; ++r) {
                int base = slot * 512 + (wave * 32 + 16 * q2 + 4 * hi + r) * 2;
                MLpart[base]     = m[q2][r];
                MLpart[base + 1] = l[q2][r];
            }
    }
}

// ---------------------------------------------------------------------------
// Flash pass 2: merge <= 16 bf16 chunk partials. 512 blocks x 128 thr.
// ---------------------------------------------------------------------------
__launch_bounds__(128)
__global__ void attn2_kernel(const unsigned short* __restrict__ Opart,
                             const float* __restrict__ MLpart,
                             float* __restrict__ out) {
    const int bid = blockIdx.x;
    const int b   = bid & 7;
    const int qt  = (bid >> 3) & 7;
    const int sub = bid >> 6;              // 0..7
    const int nch = 2 * (qt + 1);
    const int slot0 = b * 72 + qt * (qt + 1);

    const int tid  = threadIdx.x;
    const int row  = tid >> 2;             // 0..31
    const int h0   = (tid & 3) * 32;
    const int srow = sub * 32 + row;       // row within slot

    float M = -1e30f;
    for (int c = 0; c < nch; ++c)
        M = fmaxf(M, MLpart[(slot0 + c) * 512 + srow * 2]);
    float L = 0.f;
    for (int c = 0; c < nch; ++c) {
        float mc = MLpart[(slot0 + c) * 512 + srow * 2];
        float lc = MLpart[(slot0 + c) * 512 + srow * 2 + 1];
        L += lc * __expf(mc - M);
    }

    float accv[32];
    #pragma unroll
    for (int j = 0; j < 32; ++j) accv[j] = 0.f;
    for (int c = 0; c < nch; ++c) {
        float wc = __expf(MLpart[(slot0 + c) * 512 + srow * 2] - M);
        const unsigned short* src = Opart + (size_t)(slot0 + c) * 32768 + (size_t)srow * 128 + h0;
        #pragma unroll
        for (int j = 0; j < 4; ++j) {
            bf16x8 v = *(const bf16x8*)(src + j * 8);
            #pragma unroll
            for (int e = 0; e < 8; ++e)
                accv[j * 8 + e] += wc * bf2f((unsigned short)v[e]);
        }
    }
    float inv = 1.f / L;
    float4* dst = (float4*)(out + ((size_t)b * T_ + qt * 256 + srow) * H_ + h0);
    #pragma unroll
    for (int j = 0; j < 8; ++j)
        dst[j] = float4{accv[4 * j] * inv, accv[4 * j + 1] * inv,
                        accv[4 * j + 2] * inv, accv[4 * j + 3] * inv};
}

extern "C" void kernel_launch(void* const* d_in, const int* in_sizes, int n_in,
                              void* d_out, int out_size, void* d_ws, size_t ws_size,
                              hipStream_t stream) {
    const float* x  = (const float*)d_in[0];
    const float* Wq = (const float*)d_in[1];
    const float* Wk = (const float*)d_in[2];
    const float* Wv = (const float*)d_in[3];
    float* out = (float*)d_out;

    char* ws = (char*)d_ws;
    unsigned short* Wt  = (unsigned short*)ws;                          // 0.75 MB
    unsigned short* qbf = (unsigned short*)(ws + (size_t)384 * 1024 * 2);
    unsigned short* kbf = qbf + (size_t)B_ * T_ * H_;
    unsigned short* vTf = kbf + (size_t)B_ * T_ * H_;
    unsigned short* Opart = vTf + (size_t)B_ * T_ * H_;                 // 576*64KB = 36 MB
    float* MLpart = (float*)((char*)Opart + (size_t)576 * 32768 * 2);   // 1.2 MB

    wconv_kernel<<<(384 * 1024) / 256, 256, 0, stream>>>(Wq, Wk, Wv, Wt);
    gemm_kernel<<<B_ * T_ / 64, 512, 0, stream>>>(x, Wt, qbf, kbf, vTf);
    attn1_kernel<<<1024, 512, 0, stream>>>(qbf, kbf, vTf, Opart, MLpart);
    attn2_kernel<<<512, 128, 0, stream>>>(Opart, MLpart, out);
}

// Round 18
// 86.307 us; speedup vs baseline: 1.4885x; 1.0790x over previous
//
#include <hip/hip_runtime.h>
#include <hip/hip_bf16.h>

#define B_  8
#define T_  2048
#define C_  1024
#define H_  128

using f32x4  = __attribute__((ext_vector_type(4))) float;
using f32x16 = __attribute__((ext_vector_type(16))) float;
using bf16x8 = __attribute__((ext_vector_type(8))) short;

__device__ __forceinline__ unsigned short f2bf(float f) {
    union { float f; unsigned u; } v; v.f = f;
    unsigned r = v.u + 0x7FFFu + ((v.u >> 16) & 1u);   // RNE
    return (unsigned short)(r >> 16);
}
__device__ __forceinline__ float bf2f(unsigned short s) {
    union { unsigned u; float f; } v; v.u = ((unsigned)s) << 16;
    return v.f;
}

// lgkm-only barrier: LDS visibility; register-staged global loads stay in flight
#define BAR() do { asm volatile("s_waitcnt lgkmcnt(0)" ::: "memory"); \
                   __builtin_amdgcn_s_barrier(); } while (0)

// DPP cross-lane reduce within 16-lane rows (VALU-speed)
template<int C>
__device__ __forceinline__ float dppf(float v) {
    return __int_as_float(__builtin_amdgcn_update_dpp(0, __float_as_int(v), C, 0xF, 0xF, true));
}
#define DPPRED_MAX(v) { v = fmaxf(v, dppf<0xB1>(v)); v = fmaxf(v, dppf<0x4E>(v)); \
                        v = fmaxf(v, dppf<0x141>(v)); v = fmaxf(v, dppf<0x140>(v)); }
#define DPPRED_SUM(v) { v = v + dppf<0xB1>(v); v = v + dppf<0x4E>(v); \
                        v = v + dppf<0x141>(v); v = v + dppf<0x140>(v); }

// ---------------------------------------------------------------------------
// W{q,k,v} fp32 [1024][128] -> Wt K-TILED bf16: Wt[k>>5][col][k&31]
// (each 384x32 B-tile = contiguous 24 KB stream). Wq pre-scaled 1/32.
// ---------------------------------------------------------------------------
__global__ void wconv_kernel(const float* __restrict__ Wq,
                             const float* __restrict__ Wk,
                             const float* __restrict__ Wv,
                             unsigned short* __restrict__ Wt) {
    int id  = blockIdx.x * 256 + threadIdx.x;
    int col = id % 384;
    int k   = id / 384;
    const float* W = (col < 128) ? Wq : ((col < 256) ? Wk : Wv);
    float v = W[k * H_ + (col & 127)];
    if (col < 128) v *= 0.03125f;   // fold C^-0.5 into Wq (exact pow2)
    Wt[(size_t)(k >> 5) * 12288 + col * 32 + (k & 31)] = f2bf(v);
}

// ---------------------------------------------------------------------------
// Fused projection GEMM — R15-exact (proven ~44 us). 32x32x16 MFMA, BM=64.
// Grid 256 x 512 thr (8 waves: 2 row-groups x 4 col-panels; wave = 32r x 96c,
// acc = 3 x f32x16). BK=32, 32 steps, dbuf, 1 lgkm-barrier/step.
// ---------------------------------------------------------------------------
__launch_bounds__(512, 2)
__global__ void gemm_kernel(const float* __restrict__ x,
                            const unsigned short* __restrict__ Wt,
                            unsigned short* __restrict__ qb,
                            unsigned short* __restrict__ kb,
                            unsigned short* __restrict__ vT) {
    __shared__ unsigned short Bs[2][13824];   // [384 col][36], pad 32->36
    __shared__ unsigned short As[2][2304];    // [64 row][36]

    const int tid  = threadIdx.x;
    const int wave = tid >> 6;
    const int lane = tid & 63;
    const int r32 = lane & 31, hi32 = lane >> 5;
    const int row0 = blockIdx.x * 64;
    const int wrow  = (wave >> 2) * 32;
    const int wcol0 = (wave & 3) * 96;

    const int arow = tid >> 3;
    const int ak4  = (tid & 7) * 4;
    const float* xsrc = x + (size_t)(row0 + arow) * C_ + ak4;
    const unsigned short* bsrc = Wt + (size_t)tid * 8;

    f32x16 acc[3];
    #pragma unroll
    for (int ct = 0; ct < 3; ++ct)
        #pragma unroll
        for (int e = 0; e < 16; ++e) acc[ct][e] = 0.f;

    {
        #pragma unroll
        for (int j = 0; j < 3; ++j) {
            const int chunk = tid + j * 512;
            *(uint4*)&Bs[0][(chunk >> 2) * 36 + (chunk & 3) * 8] =
                *(const uint4*)(bsrc + j * 4096);
        }
        float4 f = *(const float4*)(xsrc);
        unsigned a0 = f2bf(f.x) | ((unsigned)f2bf(f.y) << 16);
        unsigned a1 = f2bf(f.z) | ((unsigned)f2bf(f.w) << 16);
        *(uint2*)&As[0][arow * 36 + ak4] = uint2{a0, a1};
    }
    float4 hA = *(const float4*)(xsrc + 32);
    float4 hB = *(const float4*)(xsrc + 64);
    BAR();

    for (int k = 0; k < 32; ++k) {
        const int cur = k & 1, nxt = cur ^ 1;

        uint4 br[3];
        float4 xf;
        if (k < 31) {
            const unsigned short* g = bsrc + (size_t)(k + 1) * 12288;
            #pragma unroll
            for (int j = 0; j < 3; ++j) br[j] = *(const uint4*)(g + j * 4096);
        }
        {
            const int kn = (k + 3 < 31) ? k + 3 : 31;
            xf = *(const float4*)(xsrc + kn * 32);
        }

        #pragma unroll
        for (int kh = 0; kh < 2; ++kh) {
            const int kofs = kh * 16 + 8 * hi32;
            bf16x8 af = *(const bf16x8*)&As[cur][(wrow + r32) * 36 + kofs];
            #pragma unroll
            for (int ct = 0; ct < 3; ++ct) {
                bf16x8 bf = *(const bf16x8*)&Bs[cur][(wcol0 + ct * 32 + r32) * 36 + kofs];
                acc[ct] = __builtin_amdgcn_mfma_f32_32x32x16_bf16(af, bf, acc[ct], 0, 0, 0);
            }
        }

        if (k < 31) {
            #pragma unroll
            for (int j = 0; j < 3; ++j) {
                const int chunk = tid + j * 512;
                *(uint4*)&Bs[nxt][(chunk >> 2) * 36 + (chunk & 3) * 8] = br[j];
            }
            unsigned a0 = f2bf(hA.x) | ((unsigned)f2bf(hA.y) << 16);
            unsigned a1 = f2bf(hA.z) | ((unsigned)f2bf(hA.w) << 16);
            *(uint2*)&As[nxt][arow * 36 + ak4] = uint2{a0, a1};
        }
        BAR();
        hA = hB; hB = xf;
    }

    #pragma unroll
    for (int ct = 0; ct < 3; ++ct) {
        int col = wcol0 + ct * 32 + r32;
        int head = col >> 7;
        int h = col & 127;
        #pragma unroll
        for (int reg = 0; reg < 16; ++reg) {
            int rg = row0 + wrow + (reg & 3) + 8 * (reg >> 2) + 4 * hi32;
            unsigned short val = f2bf(acc[ct][reg]);
            if (head == 0)      qb[(size_t)rg * H_ + h] = val;
            else if (head == 1) kb[(size_t)rg * H_ + h] = val;
            else {
                int b = rg >> 11, t = rg & (T_ - 1);
                vT[((size_t)b * H_ + h) * T_ + t] = val;
            }
        }
    }
}

// ---------------------------------------------------------------------------
// Flash pass 1 — R15 decomposition (chunk = 256 kv = 4 x KV64, grid 512)
// with DOUBLE-BUFFERED K/V LDS and ONE barrier per tile: compute(buf[cur])
// -> write(buf[cur^1] from regs prefetched 1 tile ago) -> BAR.
// Block = 8 waves; QBLK=256 (32 q-rows/wave). Partials: bf16 O.
// ---------------------------------------------------------------------------
__launch_bounds__(512, 2)
__global__ void attn1_kernel(const unsigned short* __restrict__ qb,
                             const unsigned short* __restrict__ kb,
                             const unsigned short* __restrict__ vT,
                             unsigned short* __restrict__ Opart,
                             float* __restrict__ MLpart) {
    __shared__ unsigned short Ks[2][64 * 128];   // [buf][kv][k], XOR-swizzled
    __shared__ unsigned short Vs[2][128 * 64];   // [buf][h][kv], swizzled
    __shared__ unsigned short Ps[8][16][72];     // per-wave P transpose

    const int tid  = threadIdx.x;
    const int wave = tid >> 6;
    const int lane = tid & 63;
    const int lo = lane & 15, hi = lane >> 4;

    const int bid   = blockIdx.x;
    const int b     = bid & 7;
    const int chunk = (bid >> 3) & 7;
    const int qt    = 7 - (bid >> 6);
    if (chunk > qt) return;

    const int kv_begin = chunk << 8;
    const size_t bT = (size_t)b * T_;
    const int qrow0 = (qt << 8) + wave * 32;

    const int krow = tid >> 3, kcol = (tid & 7) * 2;
    const int vrow = tid >> 2, vcol = (tid & 3) * 2;
    const unsigned short* kgsrc = kb + (bT + krow) * H_ + kcol * 8;
    const unsigned short* vgsrc = vT + ((size_t)b * H_ + vrow) * T_ + vcol * 8;
    const int koff0 = krow * 128 + ((kcol ^ (krow & 7)) * 8);
    const int koff1 = krow * 128 + (((kcol + 1) ^ (krow & 7)) * 8);
    const int voff0 = vrow * 64 + ((vcol ^ (vrow & 7)) * 8);
    const int voff1 = vrow * 64 + (((vcol + 1) ^ (vrow & 7)) * 8);

    bf16x8 qf[2][4];
    #pragma unroll
    for (int q2 = 0; q2 < 2; ++q2)
        #pragma unroll
        for (int kc = 0; kc < 4; ++kc)
            qf[q2][kc] = *(const bf16x8*)(qb + (bT + qrow0 + 16 * q2 + lo) * H_ + kc * 32 + 8 * hi);

    float m[2][4], l[2][4];
    f32x4 o[2][8];
    #pragma unroll
    for (int q2 = 0; q2 < 2; ++q2)
        #pragma unroll
        for (int r = 0; r < 4; ++r) { m[q2][r] = -1e30f; l[q2][r] = 0.f; }
    #pragma unroll
    for (int q2 = 0; q2 < 2; ++q2)
        #pragma unroll
        for (int ct = 0; ct < 8; ++ct) o[q2][ct] = f32x4{0.f, 0.f, 0.f, 0.f};

    // prologue: stage tile 0 directly; prefetch tile 1 into regs
    {
        uint4 a = *(const uint4*)(kgsrc + (size_t)kv_begin * H_);
        uint4 c = *(const uint4*)(kgsrc + (size_t)kv_begin * H_ + 8);
        uint4 d = *(const uint4*)(vgsrc + kv_begin);
        uint4 e = *(const uint4*)(vgsrc + kv_begin + 8);
        *(uint4*)&Ks[0][koff0] = a;
        *(uint4*)&Ks[0][koff1] = c;
        *(uint4*)&Vs[0][voff0] = d;
        *(uint4*)&Vs[0][voff1] = e;
    }
    uint4 kr0 = *(const uint4*)(kgsrc + (size_t)(kv_begin + 64) * H_);
    uint4 kr1 = *(const uint4*)(kgsrc + (size_t)(kv_begin + 64) * H_ + 8);
    uint4 vr0 = *(const uint4*)(vgsrc + kv_begin + 64);
    uint4 vr1 = *(const uint4*)(vgsrc + kv_begin + 64 + 8);
    BAR();

    for (int t = 0; t < 4; ++t) {
        const int cur = t & 1;
        const int kv0 = kv_begin + t * 64;

        if (kv0 <= qrow0 + 31) {
            // S = Q K^T
            f32x4 s[2][4];
            #pragma unroll
            for (int q2 = 0; q2 < 2; ++q2)
                #pragma unroll
                for (int ct4 = 0; ct4 < 4; ++ct4) s[q2][ct4] = f32x4{0.f, 0.f, 0.f, 0.f};
            __builtin_amdgcn_s_setprio(1);
            #pragma unroll
            for (int ct4 = 0; ct4 < 4; ++ct4) {
                const int row = ct4 * 16 + lo;
                #pragma unroll
                for (int kc = 0; kc < 4; ++kc) {
                    bf16x8 kf = *(const bf16x8*)&Ks[cur][row * 128 + (((kc * 4 + hi) ^ (row & 7)) * 8)];
                    s[0][ct4] = __builtin_amdgcn_mfma_f32_16x16x32_bf16(qf[0][kc], kf, s[0][ct4], 0, 0, 0);
                    s[1][ct4] = __builtin_amdgcn_mfma_f32_16x16x32_bf16(qf[1][kc], kf, s[1][ct4], 0, 0, 0);
                }
            }
            __builtin_amdgcn_s_setprio(0);

            if (kv0 + 63 >= qrow0) {
                #pragma unroll
                for (int q2 = 0; q2 < 2; ++q2)
                    #pragma unroll
                    for (int ct4 = 0; ct4 < 4; ++ct4)
                        #pragma unroll
                        for (int r = 0; r < 4; ++r)
                            if (kv0 + ct4 * 16 + lo > qrow0 + 16 * q2 + 4 * hi + r)
                                s[q2][ct4][r] = -1e30f;
            }

            float alpha[2][4];
            #pragma unroll
            for (int q2 = 0; q2 < 2; ++q2) {
                #pragma unroll
                for (int r = 0; r < 4; ++r) {
                    float pm = fmaxf(fmaxf(s[q2][0][r], s[q2][1][r]), fmaxf(s[q2][2][r], s[q2][3][r]));
                    DPPRED_MAX(pm);
                    float mn = fmaxf(m[q2][r], pm);
                    alpha[q2][r] = __expf(m[q2][r] - mn);
                    m[q2][r] = mn;
                    #pragma unroll
                    for (int ct4 = 0; ct4 < 4; ++ct4) s[q2][ct4][r] = __expf(s[q2][ct4][r] - mn);
                    float rs = (s[q2][0][r] + s[q2][1][r]) + (s[q2][2][r] + s[q2][3][r]);
                    DPPRED_SUM(rs);
                    l[q2][r] = l[q2][r] * alpha[q2][r] + rs;
                }
            }
            #pragma unroll
            for (int q2 = 0; q2 < 2; ++q2)
                #pragma unroll
                for (int ct = 0; ct < 8; ++ct)
                    #pragma unroll
                    for (int r = 0; r < 4; ++r) o[q2][ct][r] *= alpha[q2][r];

            bf16x8 pa[2][2];
            #pragma unroll
            for (int q2 = 0; q2 < 2; ++q2) {
                #pragma unroll
                for (int ct4 = 0; ct4 < 4; ++ct4)
                    #pragma unroll
                    for (int r = 0; r < 4; ++r)
                        Ps[wave][4 * hi + r][ct4 * 16 + lo] = f2bf(s[q2][ct4][r]);
                pa[q2][0] = *(const bf16x8*)&Ps[wave][lo][8 * hi];
                pa[q2][1] = *(const bf16x8*)&Ps[wave][lo][32 + 8 * hi];
            }

            __builtin_amdgcn_s_setprio(1);
            #pragma unroll
            for (int ct = 0; ct < 8; ++ct) {
                const int row = ct * 16 + lo;
                #pragma unroll
                for (int half = 0; half < 2; ++half) {
                    bf16x8 vf = *(const bf16x8*)&Vs[cur][row * 64 + (((half * 4 + hi) ^ (row & 7)) * 8)];
                    o[0][ct] = __builtin_amdgcn_mfma_f32_16x16x32_bf16(pa[0][half], vf, o[0][ct], 0, 0, 0);
                    o[1][ct] = __builtin_amdgcn_mfma_f32_16x16x32_bf16(pa[1][half], vf, o[1][ct], 0, 0, 0);
                }
            }
            __builtin_amdgcn_s_setprio(0);
        }

        if (t < 3) {
            // write buf[cur^1] from regs prefetched one tile ago
            *(uint4*)&Ks[cur ^ 1][koff0] = kr0;
            *(uint4*)&Ks[cur ^ 1][koff1] = kr1;
            *(uint4*)&Vs[cur ^ 1][voff0] = vr0;
            *(uint4*)&Vs[cur ^ 1][voff1] = vr1;
            if (t < 2) {
                const int kvn = kv_begin + (t + 2) * 64;
                kr0 = *(const uint4*)(kgsrc + (size_t)kvn * H_);
                kr1 = *(const uint4*)(kgsrc + (size_t)kvn * H_ + 8);
                vr0 = *(const uint4*)(vgsrc + kvn);
                vr1 = *(const uint4*)(vgsrc + kvn + 8);
            }
        }
        BAR();   // one barrier per tile
    }

    // write partial state (bf16 O)
    const int slot = b * 36 + ((qt * (qt + 1)) >> 1) + chunk;
    unsigned short* op = Opart + (size_t)slot * 32768 + (size_t)(wave * 32) * 128;
    #pragma unroll
    for (int q2 = 0; q2 < 2; ++q2)
        #pragma unroll
        for (int ct = 0; ct < 8; ++ct)
            #pragma unroll
            for (int r = 0; r < 4; ++r)
                op[(16 * q2 + 4 * hi + r) * 128 + ct * 16 + lo] = f2bf(o[q2][ct][r]);
    if (lo == 0) {
        #pragma unroll
        for (int q2 = 0; q2 < 2; ++q2)
            #pragma unroll
            for (int r = 0; r < 4; ++r) {
                int base = slot * 512 + (wave * 32 + 16 * q2 + 4 * hi + r) * 2;
                MLpart[base]     = m[q2][r];
                MLpart[base + 1] = l[q2][r];
            }
    }
}

// ---------------------------------------------------------------------------
// Flash pass 2: merge <= 8 bf16 chunk partials. 512 blocks x 128 thr.
// ---------------------------------------------------------------------------
__launch_bounds__(128)
__global__ void attn2_kernel(const unsigned short* __restrict__ Opart,
                             const float* __restrict__ MLpart,
                             float* __restrict__ out) {
    const int bid = blockIdx.x;
    const int b   = bid & 7;
    const int qt  = (bid >> 3) & 7;
    const int sub = bid >> 6;              // 0..7
    const int nch = qt + 1;
    const int slot0 = b * 36 + ((qt * (qt + 1)) >> 1);

    const int tid  = threadIdx.x;
    const int row  = tid >> 2;             // 0..31
    const int h0   = (tid & 3) * 32;
    const int srow = sub * 32 + row;       // row within slot

    float M = -1e30f;
    for (int c = 0; c < nch; ++c)
        M = fmaxf(M, MLpart[(slot0 + c) * 512 + srow * 2]);
    float L = 0.f;
    for (int c = 0; c < nch; ++c) {
        float mc = MLpart[(slot0 + c) * 512 + srow * 2];
        float lc = MLpart[(slot0 + c) * 512 + srow * 2 + 1];
        L += lc * __expf(mc - M);
    }

    float accv[32];
    #pragma unroll
    for (int j = 0; j < 32; ++j) accv[j] = 0.f;
    for (int c = 0; c < nch; ++c) {
        float wc = __expf(MLpart[(slot0 + c) * 512 + srow * 2] - M);
        const unsigned short* src = Opart + (size_t)(slot0 + c) * 32768 + (size_t)srow * 128 + h0;
        #pragma unroll
        for (int j = 0; j < 4; ++j) {
            bf16x8 v = *(const bf16x8*)(src + j * 8);
            #pragma unroll
            for (int e = 0; e < 8; ++e)
                accv[j * 8 + e] += wc * bf2f((unsigned short)v[e]);
        }
    }
    float inv = 1.f / L;
    float4* dst = (float4*)(out + ((size_t)b * T_ + qt * 256 + srow) * H_ + h0);
    #pragma unroll
    for (int j = 0; j < 8; ++j)
        dst[j] = float4{accv[4 * j] * inv, accv[4 * j + 1] * inv,
                        accv[4 * j + 2] * inv, accv[4 * j + 3] * inv};
}

extern "C" void kernel_launch(void* const* d_in, const int* in_sizes, int n_in,
                              void* d_out, int out_size, void* d_ws, size_t ws_size,
                              hipStream_t stream) {
    const float* x  = (const float*)d_in[0];
    const float* Wq = (const float*)d_in[1];
    const float* Wk = (const float*)d_in[2];
    const float* Wv = (const float*)d_in[3];
    float* out = (float*)d_out;

    char* ws = (char*)d_ws;
    unsigned short* Wt  = (unsigned short*)ws;                          // 0.75 MB
    unsigned short* qbf = (unsigned short*)(ws + (size_t)384 * 1024 * 2);
    unsigned short* kbf = qbf + (size_t)B_ * T_ * H_;
    unsigned short* vTf = kbf + (size_t)B_ * T_ * H_;
    unsigned short* Opart = vTf + (size_t)B_ * T_ * H_;                 // 288*64KB = 18 MB
    float* MLpart = (float*)((char*)Opart + (size_t)288 * 32768 * 2);   // 0.56 MB

    wconv_kernel<<<(384 * 1024) / 256, 256, 0, stream>>>(Wq, Wk, Wv, Wt);
    gemm_kernel<<<B_ * T_ / 64, 512, 0, stream>>>(x, Wt, qbf, kbf, vTf);
    attn1_kernel<<<512, 512, 0, stream>>>(qbf, kbf, vTf, Opart, MLpart);
    attn2_kernel<<<512, 128, 0, stream>>>(Opart, MLpart, out);
}